// Round 1
// baseline (129.579 us; speedup 1.0000x reference)
//
#include <hip/hip_runtime.h>
#include <math.h>

#define FF 20
#define TPB 256
#define RPT 4

// ---------------------------------------------------------------------------
// Setup: A = W^T @ R (stored transposed: At[m][i] = sum_j W[j,i]*R[j,m]),
//        c[m] = sum_j b[j]*R[j,m] + 1, and zero the two double accumulators.
// ---------------------------------------------------------------------------
__global__ void mlp_setup(const float* __restrict__ W, const float* __restrict__ b,
                          const float* __restrict__ R, float* __restrict__ Af,
                          double* __restrict__ sums) {
    int t = threadIdx.x;
    if (t < 2) sums[t] = 0.0;
    if (t < FF * FF) {
        int m = t / FF, i = t % FF;
        float s = 0.f;
        #pragma unroll
        for (int j = 0; j < FF; ++j) s = fmaf(W[j * FF + i], R[j * FF + m], s);
        Af[m * FF + i] = s;                 // At[m*FF + i], contiguous in i
    } else if (t < FF * FF + FF) {
        int m = t - FF * FF;
        float s = 1.0f;
        #pragma unroll
        for (int j = 0; j < FF; ++j) s = fmaf(b[j], R[j * FF + m], s);
        Af[FF * FF + m] = s;                // c[m]
    }
}

// ---------------------------------------------------------------------------
// Main: per thread, RPT rows. h2 = relu(x·A + c); h3 = h2·W^T + b;
// accumulate sum(h3) and sum(|h3|) -> wave reduce -> global double atomics.
// ---------------------------------------------------------------------------
__global__ __launch_bounds__(TPB) void mlp_main(
    const float* __restrict__ x, const float* __restrict__ W,
    const float* __restrict__ b, const float* __restrict__ Af,
    double* __restrict__ sums, int nrows)
{
    __shared__ float sAt[FF * FF];
    __shared__ float sW[FF * FF];
    __shared__ float sc[FF];
    __shared__ float sb[FF];
    int t = threadIdx.x;
    for (int u = t; u < FF * FF; u += TPB) { sAt[u] = Af[u]; sW[u] = W[u]; }
    if (t < FF) { sc[t] = Af[FF * FF + t]; sb[t] = b[t]; }
    __syncthreads();

    const int gid = blockIdx.x * TPB + t;
    const int stride = gridDim.x * TPB;

    // Load RPT rows of x (5x float4 per row; rows are 80B = 16B-aligned).
    float xr[RPT][FF];
    #pragma unroll
    for (int r = 0; r < RPT; ++r) {
        int row = gid + r * stride;
        if (row < nrows) {
            const float4* xp = reinterpret_cast<const float4*>(x + (size_t)row * FF);
            #pragma unroll
            for (int u = 0; u < FF / 4; ++u)
                *reinterpret_cast<float4*>(&xr[r][4 * u]) = xp[u];
        } else {
            #pragma unroll
            for (int i = 0; i < FF; ++i) xr[r][i] = 0.f;
        }
    }

    // Phase 1: h2[r][m] = relu(sum_i xr[r][i] * At[m][i] + c[m])
    float h2[RPT][FF];
    #pragma unroll
    for (int m = 0; m < FF; ++m) {
        float acc[RPT];
        #pragma unroll
        for (int r = 0; r < RPT; ++r) acc[r] = sc[m];
        #pragma unroll
        for (int u = 0; u < FF / 4; ++u) {
            float4 a4 = *reinterpret_cast<const float4*>(&sAt[m * FF + 4 * u]);
            #pragma unroll
            for (int r = 0; r < RPT; ++r) {
                acc[r] = fmaf(xr[r][4 * u + 0], a4.x, acc[r]);
                acc[r] = fmaf(xr[r][4 * u + 1], a4.y, acc[r]);
                acc[r] = fmaf(xr[r][4 * u + 2], a4.z, acc[r]);
                acc[r] = fmaf(xr[r][4 * u + 3], a4.w, acc[r]);
            }
        }
        #pragma unroll
        for (int r = 0; r < RPT; ++r) h2[r][m] = fmaxf(acc[r], 0.f);
    }

    // Phase 2: h3[r][n] = sum_m h2[r][m] * W[n][m] + b[n]; reduce sum & |sum|.
    float psum[RPT], pabs[RPT];
    #pragma unroll
    for (int r = 0; r < RPT; ++r) { psum[r] = 0.f; pabs[r] = 0.f; }
    #pragma unroll
    for (int n = 0; n < FF; ++n) {
        float acc[RPT];
        #pragma unroll
        for (int r = 0; r < RPT; ++r) acc[r] = sb[n];
        #pragma unroll
        for (int u = 0; u < FF / 4; ++u) {
            float4 w4 = *reinterpret_cast<const float4*>(&sW[n * FF + 4 * u]);
            #pragma unroll
            for (int r = 0; r < RPT; ++r) {
                acc[r] = fmaf(h2[r][4 * u + 0], w4.x, acc[r]);
                acc[r] = fmaf(h2[r][4 * u + 1], w4.y, acc[r]);
                acc[r] = fmaf(h2[r][4 * u + 2], w4.z, acc[r]);
                acc[r] = fmaf(h2[r][4 * u + 3], w4.w, acc[r]);
            }
        }
        #pragma unroll
        for (int r = 0; r < RPT; ++r) {
            psum[r] += acc[r];
            pabs[r] += fabsf(acc[r]);
        }
    }

    float ssum = 0.f, sabs = 0.f;
    #pragma unroll
    for (int r = 0; r < RPT; ++r) {
        if (gid + r * stride < nrows) { ssum += psum[r]; sabs += pabs[r]; }
    }

    // wave(64) reduction
    #pragma unroll
    for (int off = 32; off > 0; off >>= 1) {
        ssum += __shfl_down(ssum, off, 64);
        sabs += __shfl_down(sabs, off, 64);
    }
    if ((t & 63) == 0) {
        atomicAdd(&sums[0], (double)ssum);
        atomicAdd(&sums[1], (double)sabs);
    }
}

// ---------------------------------------------------------------------------
// Epilogue: k = number of halvings until sum|h| <= 1; out = sum(h) * 2^-k.
// ---------------------------------------------------------------------------
__global__ void mlp_final(const double* __restrict__ sums, float* __restrict__ out) {
    double s = sums[1];
    int k = 0;
    while (s > 1.0 && k < 4000) { s *= 0.5; ++k; }
    out[0] = (float)ldexp(sums[0], -k);
}

extern "C" void kernel_launch(void* const* d_in, const int* in_sizes, int n_in,
                              void* d_out, int out_size, void* d_ws, size_t ws_size,
                              hipStream_t stream) {
    const float* x = (const float*)d_in[0];
    const float* W = (const float*)d_in[1];
    const float* b = (const float*)d_in[2];
    const float* R = (const float*)d_in[3];
    float* out = (float*)d_out;

    double* sums = (double*)d_ws;              // 2 doubles
    float* Af = (float*)d_ws + 4;              // At (400) + c (20)

    int nrows = in_sizes[0] / FF;

    hipLaunchKernelGGL(mlp_setup, dim3(1), dim3(448), 0, stream, W, b, R, Af, sums);
    int blocks = (nrows + TPB * RPT - 1) / (TPB * RPT);
    hipLaunchKernelGGL(mlp_main, dim3(blocks), dim3(TPB), 0, stream,
                       x, W, b, Af, sums, nrows);
    hipLaunchKernelGGL(mlp_final, dim3(1), dim3(1), 0, stream, sums, out);
}

// Round 2
// 44.767 us; speedup vs baseline: 2.8945x; 2.8945x over previous
//
#include <hip/hip_runtime.h>
#include <math.h>

#define FF 20
#define TPB 256
#define RPT 4

// ---------------------------------------------------------------------------
// Setup: A = W^T @ R (stored transposed: At[m][i] = sum_j W[j,i]*R[j,m]),
//        c[m] = sum_j b[j]*R[j,m] + 1.
// ---------------------------------------------------------------------------
__global__ void mlp_setup(const float* __restrict__ W, const float* __restrict__ b,
                          const float* __restrict__ R, float* __restrict__ Af) {
    int t = threadIdx.x;
    if (t < FF * FF) {
        int m = t / FF, i = t % FF;
        float s = 0.f;
        #pragma unroll
        for (int j = 0; j < FF; ++j) s = fmaf(W[j * FF + i], R[j * FF + m], s);
        Af[m * FF + i] = s;                 // At[m*FF + i], contiguous in i
    } else if (t < FF * FF + FF) {
        int m = t - FF * FF;
        float s = 1.0f;
        #pragma unroll
        for (int j = 0; j < FF; ++j) s = fmaf(b[j], R[j * FF + m], s);
        Af[FF * FF + m] = s;                // c[m]
    }
}

// ---------------------------------------------------------------------------
// Main: per thread, RPT rows. h2 = relu(x·A + c); h3 = h2·W^T + b;
// accumulate sum(h3) and sum(|h3|) -> wave reduce -> LDS block reduce ->
// one double2 partial per block (NO global atomics).
// ---------------------------------------------------------------------------
__global__ __launch_bounds__(TPB) void mlp_main(
    const float* __restrict__ x, const float* __restrict__ W,
    const float* __restrict__ b, const float* __restrict__ Af,
    double2* __restrict__ partials, int nrows)
{
    __shared__ float sAt[FF * FF];
    __shared__ float sW[FF * FF];
    __shared__ float sc[FF];
    __shared__ float sb[FF];
    __shared__ double wsum[TPB / 64], wabs[TPB / 64];
    int t = threadIdx.x;
    for (int u = t; u < FF * FF; u += TPB) { sAt[u] = Af[u]; sW[u] = W[u]; }
    if (t < FF) { sc[t] = Af[FF * FF + t]; sb[t] = b[t]; }
    __syncthreads();

    const int gid = blockIdx.x * TPB + t;
    const int stride = gridDim.x * TPB;

    // Load RPT rows of x (5x float4 per row; rows are 80B = 16B-aligned).
    float xr[RPT][FF];
    #pragma unroll
    for (int r = 0; r < RPT; ++r) {
        int row = gid + r * stride;
        if (row < nrows) {
            const float4* xp = reinterpret_cast<const float4*>(x + (size_t)row * FF);
            #pragma unroll
            for (int u = 0; u < FF / 4; ++u)
                *reinterpret_cast<float4*>(&xr[r][4 * u]) = xp[u];
        } else {
            #pragma unroll
            for (int i = 0; i < FF; ++i) xr[r][i] = 0.f;
        }
    }

    // Phase 1: h2[r][m] = relu(sum_i xr[r][i] * At[m][i] + c[m])
    float h2[RPT][FF];
    #pragma unroll
    for (int m = 0; m < FF; ++m) {
        float acc[RPT];
        #pragma unroll
        for (int r = 0; r < RPT; ++r) acc[r] = sc[m];
        #pragma unroll
        for (int u = 0; u < FF / 4; ++u) {
            float4 a4 = *reinterpret_cast<const float4*>(&sAt[m * FF + 4 * u]);
            #pragma unroll
            for (int r = 0; r < RPT; ++r) {
                acc[r] = fmaf(xr[r][4 * u + 0], a4.x, acc[r]);
                acc[r] = fmaf(xr[r][4 * u + 1], a4.y, acc[r]);
                acc[r] = fmaf(xr[r][4 * u + 2], a4.z, acc[r]);
                acc[r] = fmaf(xr[r][4 * u + 3], a4.w, acc[r]);
            }
        }
        #pragma unroll
        for (int r = 0; r < RPT; ++r) h2[r][m] = fmaxf(acc[r], 0.f);
    }

    // Phase 2: h3[r][n] = sum_m h2[r][m] * W[n][m] + b[n]; reduce sum & |sum|.
    float psum[RPT], pabs[RPT];
    #pragma unroll
    for (int r = 0; r < RPT; ++r) { psum[r] = 0.f; pabs[r] = 0.f; }
    #pragma unroll
    for (int n = 0; n < FF; ++n) {
        float acc[RPT];
        #pragma unroll
        for (int r = 0; r < RPT; ++r) acc[r] = sb[n];
        #pragma unroll
        for (int u = 0; u < FF / 4; ++u) {
            float4 w4 = *reinterpret_cast<const float4*>(&sW[n * FF + 4 * u]);
            #pragma unroll
            for (int r = 0; r < RPT; ++r) {
                acc[r] = fmaf(h2[r][4 * u + 0], w4.x, acc[r]);
                acc[r] = fmaf(h2[r][4 * u + 1], w4.y, acc[r]);
                acc[r] = fmaf(h2[r][4 * u + 2], w4.z, acc[r]);
                acc[r] = fmaf(h2[r][4 * u + 3], w4.w, acc[r]);
            }
        }
        #pragma unroll
        for (int r = 0; r < RPT; ++r) {
            psum[r] += acc[r];
            pabs[r] += fabsf(acc[r]);
        }
    }

    float ssum = 0.f, sabs = 0.f;
    #pragma unroll
    for (int r = 0; r < RPT; ++r) {
        if (gid + r * stride < nrows) { ssum += psum[r]; sabs += pabs[r]; }
    }

    // wave(64) reduction
    #pragma unroll
    for (int off = 32; off > 0; off >>= 1) {
        ssum += __shfl_down(ssum, off, 64);
        sabs += __shfl_down(sabs, off, 64);
    }
    if ((t & 63) == 0) {
        wsum[t >> 6] = (double)ssum;
        wabs[t >> 6] = (double)sabs;
    }
    __syncthreads();
    if (t == 0) {
        double bs = 0.0, ba = 0.0;
        #pragma unroll
        for (int w = 0; w < TPB / 64; ++w) { bs += wsum[w]; ba += wabs[w]; }
        partials[blockIdx.x] = make_double2(bs, ba);
    }
}

// ---------------------------------------------------------------------------
// Final: tree-reduce block partials (fixed order -> deterministic), compute
// k = number of halvings until sum|h| <= 1; out = sum(h) * 2^-k.
// ---------------------------------------------------------------------------
__global__ __launch_bounds__(256) void mlp_final(const double2* __restrict__ parts,
                                                 int nparts, float* __restrict__ out) {
    __shared__ double s_sum[256], s_abs[256];
    int t = threadIdx.x;
    double a = 0.0, sg = 0.0;
    for (int i = t; i < nparts; i += 256) { sg += parts[i].x; a += parts[i].y; }
    s_sum[t] = sg; s_abs[t] = a;
    __syncthreads();
    for (int off = 128; off > 0; off >>= 1) {
        if (t < off) { s_sum[t] += s_sum[t + off]; s_abs[t] += s_abs[t + off]; }
        __syncthreads();
    }
    if (t == 0) {
        double s = s_abs[0];
        int k = 0;
        while (s > 1.0 && k < 4000) { s *= 0.5; ++k; }
        out[0] = (float)ldexp(s_sum[0], -k);
    }
}

extern "C" void kernel_launch(void* const* d_in, const int* in_sizes, int n_in,
                              void* d_out, int out_size, void* d_ws, size_t ws_size,
                              hipStream_t stream) {
    const float* x = (const float*)d_in[0];
    const float* W = (const float*)d_in[1];
    const float* b = (const float*)d_in[2];
    const float* R = (const float*)d_in[3];
    float* out = (float*)d_out;

    // d_ws layout: [0, 2KB) Af (440 floats used), [2KB, ...) double2 partials
    float* Af = (float*)d_ws;
    double2* partials = (double2*)((char*)d_ws + 2048);

    int nrows = in_sizes[0] / FF;
    int blocks = (nrows + TPB * RPT - 1) / (TPB * RPT);

    hipLaunchKernelGGL(mlp_setup, dim3(1), dim3(448), 0, stream, W, b, R, Af);
    hipLaunchKernelGGL(mlp_main, dim3(blocks), dim3(TPB), 0, stream,
                       x, W, b, Af, partials, nrows);
    hipLaunchKernelGGL(mlp_final, dim3(1), dim3(256), 0, stream, partials, blocks, out);
}

// Round 4
// 29.170 us; speedup vs baseline: 4.4421x; 1.5347x over previous
//
#include <hip/hip_runtime.h>
#include <math.h>

#define FF 20
#define TPB 256              // 4 waves per block
#define TILES_PER_WAVE 16    // 16 rows per tile -> 256 rows per wave
#define BT 4                 // tiles per load batch

typedef __fp16 half2v __attribute__((ext_vector_type(2)));
typedef __fp16 half8 __attribute__((ext_vector_type(8)));
typedef float f32x4 __attribute__((ext_vector_type(4)));

// ---------------------------------------------------------------------------
// Setup: build the four A-fragments (f16, per-lane layout for 16x16x32 MFMA)
//   f=0,1: GEMM1 A = At_ext, row m = (f&1)*16 + (l&15), k = i
//          At[m][i] = sum_j W[j,i] R[j,m]  (i<20);  i==20 -> c[m]=sum_j b_j R[j,m]+1
//   f=2,3: GEMM2 A = W_ext, row n = (f&1)*16 + (l&15), k = m
//          W[n][m] (m<20); m==20 -> b[n]
//   k(e) = e<4 ? 4g+e : 16+4g+(e-4), g = (l>>4)
// ---------------------------------------------------------------------------
__global__ void mlp_setup(const float* __restrict__ W, const float* __restrict__ b,
                          const float* __restrict__ R, __fp16* __restrict__ frag) {
    int t = threadIdx.x;                 // t = f*64 + l, 256 threads
    int f = t >> 6, l = t & 63;
    int g = l >> 4, p = l & 15;
    int row = (f & 1) * 16 + p;
    #pragma unroll
    for (int e = 0; e < 8; ++e) {
        int k = (e < 4) ? (4 * g + e) : (16 + 4 * g + (e - 4));
        float v = 0.f;
        if (f < 2) {                     // GEMM1 weights
            if (row < FF) {
                if (k < FF) {
                    float s = 0.f;
                    for (int j = 0; j < FF; ++j) s = fmaf(W[j * FF + k], R[j * FF + row], s);
                    v = s;
                } else if (k == FF) {
                    float s = 1.0f;
                    for (int j = 0; j < FF; ++j) s = fmaf(b[j], R[j * FF + row], s);
                    v = s;
                }
            }
        } else {                         // GEMM2 weights
            if (row < FF) {
                if (k < FF) v = W[row * FF + k];
                else if (k == FF) v = b[row];
            }
        }
        frag[t * 8 + e] = (__fp16)v;
    }
}

// ---------------------------------------------------------------------------
// Main: each wave handles TILES_PER_WAVE contiguous 16-row tiles.
// Per tile: B1 = xT frag (f16) -> 2 MFMA (h2T) -> relu+pack -> 2 MFMA (h3T)
// -> accumulate sum / abs-sum per lane. No LDS in the loop, no spills.
// ---------------------------------------------------------------------------
__global__ __launch_bounds__(TPB) void mlp_main(
    const float* __restrict__ x, const __fp16* __restrict__ frag,
    double2* __restrict__ partials, int nrows, int ntiles)
{
    const int t = threadIdx.x;
    const int l = t & 63;
    const int g = l >> 4;        // 0..3
    const int r = l & 15;        // row within tile == output col

    // persistent A-fragments (16 VGPRs)
    const half8 A10 = *reinterpret_cast<const half8*>(frag + (0 * 64 + l) * 8);
    const half8 A11 = *reinterpret_cast<const half8*>(frag + (1 * 64 + l) * 8);
    const half8 A20 = *reinterpret_cast<const half8*>(frag + (2 * 64 + l) * 8);
    const half8 A21 = *reinterpret_cast<const half8*>(frag + (3 * 64 + l) * 8);

    const int wave_id = blockIdx.x * (TPB / 64) + (t >> 6);
    const long tile0 = (long)wave_id * TILES_PER_WAVE;

    float psum = 0.f, pabs = 0.f;
    const f32x4 zero = {0.f, 0.f, 0.f, 0.f};

    for (int bt = 0; bt < TILES_PER_WAVE / BT; ++bt) {
        float4 xa[BT], xb[BT];
        #pragma unroll
        for (int u = 0; u < BT; ++u) {
            long tile = tile0 + bt * BT + u;
            xa[u] = make_float4(0.f, 0.f, 0.f, 0.f);
            xb[u] = make_float4(0.f, 0.f, 0.f, 0.f);
            if (tile < ntiles) {
                long row = tile * 16 + r;
                if (row < nrows) {
                    const float* rowp = x + row * FF;
                    xa[u] = *reinterpret_cast<const float4*>(rowp + 4 * g);
                    if (g == 0)
                        xb[u] = *reinterpret_cast<const float4*>(rowp + 16);
                }
            }
        }
        #pragma unroll
        for (int u = 0; u < BT; ++u) {
            long tile = tile0 + bt * BT + u;
            // ---- B1 fragment: x row r, k=i per doubled-K layout ----
            half8 B1;
            half2v p0 = __builtin_amdgcn_cvt_pkrtz(xa[u].x, xa[u].y);
            half2v p1 = __builtin_amdgcn_cvt_pkrtz(xa[u].z, xa[u].w);
            B1[0] = p0[0]; B1[1] = p0[1]; B1[2] = p1[0]; B1[3] = p1[1];
            if (g == 0) {
                half2v p2 = __builtin_amdgcn_cvt_pkrtz(xb[u].x, xb[u].y);
                half2v p3 = __builtin_amdgcn_cvt_pkrtz(xb[u].z, xb[u].w);
                B1[4] = p2[0]; B1[5] = p2[1]; B1[6] = p3[0]; B1[7] = p3[1];
            } else if (g == 1) {
                B1[4] = (__fp16)1.0f;     // i == 20 -> constant-1 (bias column)
                B1[5] = (__fp16)0.f; B1[6] = (__fp16)0.f; B1[7] = (__fp16)0.f;
            } else {
                B1[4] = (__fp16)0.f; B1[5] = (__fp16)0.f;
                B1[6] = (__fp16)0.f; B1[7] = (__fp16)0.f;
            }
            // ---- GEMM1: h2T[m][r], m-tiles 0-15 / 16-31 ----
            f32x4 c0 = __builtin_amdgcn_mfma_f32_16x16x32_f16(A10, B1, zero, 0, 0, 0);
            f32x4 c1 = __builtin_amdgcn_mfma_f32_16x16x32_f16(A11, B1, zero, 0, 0, 0);
            // ---- relu + pack: lane's m = {4g+reg} u {16+4g+reg} == B2's k-pattern ----
            half8 B2;
            half2v q0 = __builtin_amdgcn_cvt_pkrtz(fmaxf(c0[0], 0.f), fmaxf(c0[1], 0.f));
            half2v q1 = __builtin_amdgcn_cvt_pkrtz(fmaxf(c0[2], 0.f), fmaxf(c0[3], 0.f));
            half2v q2 = __builtin_amdgcn_cvt_pkrtz(fmaxf(c1[0], 0.f), fmaxf(c1[1], 0.f));
            half2v q3 = __builtin_amdgcn_cvt_pkrtz(fmaxf(c1[2], 0.f), fmaxf(c1[3], 0.f));
            B2[0] = q0[0]; B2[1] = q0[1]; B2[2] = q1[0]; B2[3] = q1[1];
            B2[4] = q2[0]; B2[5] = q2[1]; B2[6] = q3[0]; B2[7] = q3[1];
            if (g == 1) B2[4] = (__fp16)1.0f;   // m == 20 -> constant-1 (bias column)
            // ---- GEMM2: h3T[n][r], n-tiles 0-15 / 16-31 ----
            f32x4 d0 = __builtin_amdgcn_mfma_f32_16x16x32_f16(A20, B2, zero, 0, 0, 0);
            f32x4 d1 = __builtin_amdgcn_mfma_f32_16x16x32_f16(A21, B2, zero, 0, 0, 0);
            // ---- accumulate (pad n rows are exactly 0) ----
            if (tile * 16 + r < nrows) {
                #pragma unroll
                for (int q = 0; q < 4; ++q) {
                    psum += d0[q];            pabs += fabsf(d0[q]);
                    psum += d1[q];            pabs += fabsf(d1[q]);
                }
            }
        }
    }

    // wave(64) reduction
    #pragma unroll
    for (int off = 32; off > 0; off >>= 1) {
        psum += __shfl_down(psum, off, 64);
        pabs += __shfl_down(pabs, off, 64);
    }
    __shared__ double wsum[TPB / 64], wabs[TPB / 64];
    if ((t & 63) == 0) { wsum[t >> 6] = (double)psum; wabs[t >> 6] = (double)pabs; }
    __syncthreads();
    if (t == 0) {
        double bs = 0.0, ba = 0.0;
        #pragma unroll
        for (int w = 0; w < TPB / 64; ++w) { bs += wsum[w]; ba += wabs[w]; }
        partials[blockIdx.x] = make_double2(bs, ba);
    }
}

// ---------------------------------------------------------------------------
// Final: deterministic tree-reduce of block partials; halving count; output.
// ---------------------------------------------------------------------------
__global__ __launch_bounds__(256) void mlp_final(const double2* __restrict__ parts,
                                                 int nparts, float* __restrict__ out) {
    __shared__ double s_sum[256], s_abs[256];
    int t = threadIdx.x;
    double a = 0.0, sg = 0.0;
    for (int i = t; i < nparts; i += 256) { sg += parts[i].x; a += parts[i].y; }
    s_sum[t] = sg; s_abs[t] = a;
    __syncthreads();
    for (int off = 128; off > 0; off >>= 1) {
        if (t < off) { s_sum[t] += s_sum[t + off]; s_abs[t] += s_abs[t + off]; }
        __syncthreads();
    }
    if (t == 0) {
        double s = s_abs[0];
        int k = 0;
        while (s > 1.0 && k < 4000) { s *= 0.5; ++k; }
        out[0] = (float)ldexp(s_sum[0], -k);
    }
}

extern "C" void kernel_launch(void* const* d_in, const int* in_sizes, int n_in,
                              void* d_out, int out_size, void* d_ws, size_t ws_size,
                              hipStream_t stream) {
    const float* x = (const float*)d_in[0];
    const float* W = (const float*)d_in[1];
    const float* b = (const float*)d_in[2];
    const float* R = (const float*)d_in[3];
    float* out = (float*)d_out;

    // d_ws: [0, 4KB) A-fragments (4*64*8 f16), [8KB, ...) double2 partials
    __fp16* frag = (__fp16*)d_ws;
    double2* partials = (double2*)((char*)d_ws + 8192);

    int nrows = in_sizes[0] / FF;
    int ntiles = (nrows + 15) / 16;
    int waves = (ntiles + TILES_PER_WAVE - 1) / TILES_PER_WAVE;
    int blocks = (waves + (TPB / 64) - 1) / (TPB / 64);

    hipLaunchKernelGGL(mlp_setup, dim3(1), dim3(256), 0, stream, W, b, R, frag);
    hipLaunchKernelGGL(mlp_main, dim3(blocks), dim3(TPB), 0, stream,
                       x, frag, partials, nrows, ntiles);
    hipLaunchKernelGGL(mlp_final, dim3(1), dim3(256), 0, stream, partials, blocks, out);
}